// Round 9
// baseline (659.234 us; speedup 1.0000x reference)
//
#include <hip/hip_runtime.h>
#include <stdint.h>

#define BATCH 512
#define SEQ   512
#define HID   128
#define BT    16        // batch tile per block
#define XROW  272       // LDS row stride bytes (128 f16 data + 16B pad)
#define XSZ   (BT*XROW) // 4352B per buffer
#define NTILE 32        // BATCH/BT
#define CH    8         // steps per done-chunk (back-pressure only)
#define RING  64        // ring slots (steps) per layer boundary
#define FPAD  32        // ints per flag (128B line)
#define SKEW  8         // startup lag consumers establish vs producer

typedef _Float16 half8 __attribute__((ext_vector_type(8)));
typedef float f32x4 __attribute__((ext_vector_type(4)));
typedef unsigned long long u64;

union UHP { uint32_t u; _Float16 h[2]; };
__device__ __forceinline__ uint32_t pack2f(float a, float b){
  UHP r; r.h[0] = (_Float16)a; r.h[1] = (_Float16)b; return r.u;
}
__device__ __forceinline__ float unpk(uint32_t u, int i){
  UHP r; r.u = u; return (float)r.h[i];
}

__device__ __forceinline__ float rcp_(float x){
#if __has_builtin(__builtin_amdgcn_rcpf)
  return __builtin_amdgcn_rcpf(x);
#else
  return 1.f / x;
#endif
}
__device__ __forceinline__ float exp2_(float x){
#if __has_builtin(__builtin_amdgcn_exp2f)
  return __builtin_amdgcn_exp2f(x);
#else
  return exp2f(x);
#endif
}
__device__ __forceinline__ float sigm(float x){ return rcp_(1.f + exp2_(x * -1.44269504f)); }
__device__ __forceinline__ float tanh_(float x){ return 1.f - 2.f * rcp_(exp2_(x * 2.88539008f) + 1.f); }

__device__ __forceinline__ int aload(const int* p){
  return __hip_atomic_load(p, __ATOMIC_RELAXED, __HIP_MEMORY_SCOPE_AGENT);
}

// MODE 0: x fp32 -> ring0 ; MODE 1: ring0 -> ring1 ; MODE 2: ring1 -> y fp32
//
// Round-9 structure: xg-split. acc[g] carries bias + Wih*x(t) across the
// barrier (computed off-path at step t-1). Step t's critical path is only
// acc += Whh*h(t-1) (4 dependent MFMAs/gate) + elementwise. After the gates
// are read, the SAME acc regs are re-inited to bias + Wih*x(t+1).
// x: triple-buffered LDS (read t+1 / write t+2, one barrier apart).
// h: double-buffered LDS.
template<int MODE>
__device__ __forceinline__ void run_layer(
    const float* __restrict__ Wih, const float* __restrict__ Whh,
    const float* __restrict__ bih, const float* __restrict__ bhh,
    const float* __restrict__ x, uint32_t* __restrict__ rin,
    uint32_t* __restrict__ rout, float* __restrict__ y,
    int* src_ready, int* src_done, int* dst_ready, int* dst_done,
    int b0, char* xb, char* hb)
{
  const int tid  = threadIdx.x;
  const int lane = tid & 63;
  const int w    = tid >> 6;
  const int u0   = w * 16;
  const int rm   = lane & 15;   // batch col within tile
  const int kq   = lane >> 4;   // k-quarter / acc row group

  // ---- weights -> f16 register fragments (A: 16 units x 32 k per frag)
  half8 wih[4][4], whh[4][4];
  #pragma unroll
  for (int g = 0; g < 4; ++g){
    const int grow = g * HID + u0 + rm;
    #pragma unroll
    for (int s = 0; s < 4; ++s){
      const int k = s * 32 + kq * 8;
      const float* si = Wih + (size_t)grow * HID + k;
      const float* sh = Whh + (size_t)grow * HID + k;
      float4 aa = *(const float4*)si, bb = *(const float4*)(si + 4);
      half8 hi;
      hi[0]=(_Float16)aa.x; hi[1]=(_Float16)aa.y; hi[2]=(_Float16)aa.z; hi[3]=(_Float16)aa.w;
      hi[4]=(_Float16)bb.x; hi[5]=(_Float16)bb.y; hi[6]=(_Float16)bb.z; hi[7]=(_Float16)bb.w;
      wih[g][s] = hi;
      aa = *(const float4*)sh; bb = *(const float4*)(sh + 4);
      half8 hh;
      hh[0]=(_Float16)aa.x; hh[1]=(_Float16)aa.y; hh[2]=(_Float16)aa.z; hh[3]=(_Float16)aa.w;
      hh[4]=(_Float16)bb.x; hh[5]=(_Float16)bb.y; hh[6]=(_Float16)bb.z; hh[7]=(_Float16)bb.w;
      whh[g][s] = hh;
    }
  }
  f32x4 bias4[4];
  #pragma unroll
  for (int g = 0; g < 4; ++g)
    #pragma unroll
    for (int r = 0; r < 4; ++r){
      const int row = g * HID + u0 + kq * 4 + r;
      bias4[g][r] = bih[row] + bhh[row];
    }

  // ---- staging thread mapping: 16 rows x 128 f16
  const int sb = tid >> 5;   // 0..15 batch row
  const int sk = tid & 31;   // col group (8B)

  auto xaddr = [&](int t){
    return (const float4*)(x + ((size_t)(b0 + sb) * SEQ + t) * HID + sk * 4);
  };
  auto raddr = [&](int t){
    return (u64*)(rin + ((size_t)(t & (RING-1)) * BATCH + b0 + sb) * 64 + sk * 2);
  };

  float4 pfa, pfb;         // MODE 0: x prefetch (cur / nxt)
  u64    pga = 0, pgb = 0; // MODE 1/2: ring prefetch

  int fseen = 0, fpend = 0, dseen = 0;

  // ---- prologue: SKEW lag, stage x(0)->xb0, x(1)->xb1, preload x(2)
  if constexpr (MODE != 0){
    fseen = aload(src_ready);
    while (fseen < SKEW){ __builtin_amdgcn_s_sleep(8); fseen = aload(src_ready); }
  }
  if constexpr (MODE == 0){
    float4 v = *xaddr(0);
    uint2 p; p.x = pack2f(v.x, v.y); p.y = pack2f(v.z, v.w);
    *(uint2*)(xb + sb * XROW + sk * 8) = p;
    v = *xaddr(1);
    p.x = pack2f(v.x, v.y); p.y = pack2f(v.z, v.w);
    *(uint2*)(xb + XSZ + sb * XROW + sk * 8) = p;
    pfa = *xaddr(2);
  } else {
    u64 v = __hip_atomic_load(raddr(0), __ATOMIC_RELAXED, __HIP_MEMORY_SCOPE_AGENT);
    *(u64*)(xb + sb * XROW + sk * 8) = v;
    v = __hip_atomic_load(raddr(1), __ATOMIC_RELAXED, __HIP_MEMORY_SCOPE_AGENT);
    *(u64*)(xb + XSZ + sb * XROW + sk * 8) = v;
    pga = __hip_atomic_load(raddr(2), __ATOMIC_RELAXED, __HIP_MEMORY_SCOPE_AGENT);
    fpend = aload(src_ready);
  }
  if (tid < 256)
    *(uint4*)(hb + (tid >> 4) * XROW + (tid & 15) * 16) = make_uint4(0u,0u,0u,0u);
  __syncthreads();

  // ---- acc init for t=0: bias + Wih*x(0) from xb[0]
  const int foff = rm * XROW + kq * 16;
  f32x4 a0 = bias4[0], a1 = bias4[1], a2 = bias4[2], a3 = bias4[3];
  #pragma unroll
  for (int s = 0; s < 4; ++s){
    const half8 bf = *(const half8*)(xb + foff + s * 64);
    a0 = __builtin_amdgcn_mfma_f32_16x16x32_f16(wih[0][s], bf, a0, 0, 0, 0);
    a1 = __builtin_amdgcn_mfma_f32_16x16x32_f16(wih[1][s], bf, a1, 0, 0, 0);
    a2 = __builtin_amdgcn_mfma_f32_16x16x32_f16(wih[2][s], bf, a2, 0, 0, 0);
    a3 = __builtin_amdgcn_mfma_f32_16x16x32_f16(wih[3][s], bf, a3, 0, 0, 0);
  }

  f32x4 c4 = {0.f, 0.f, 0.f, 0.f};
  int cur = 0, xr = 1, xw = 2;
  uint2 hp = {0u, 0u};     // deferred-store state (h of step t-1, f16 packed)

  for (int t = 0; t < SEQ; ++t){
    char* hbc = hb + cur * XSZ;
    char* hbn = hb + (cur ^ 1) * XSZ;
    char* xbr = xb + xr * XSZ;
    char* xbw = xb + xw * XSZ;
    const int tn = t + 1;

    // ---- flush deferred global store of h(t-1)
    if (t > 0){
      if constexpr (MODE != 2){
        const u64 hp64 = ((u64)hp.y << 32) | (u64)hp.x;
        u64* p = (u64*)(rout + ((size_t)((t-1) & (RING-1)) * BATCH + b0 + rm) * 64 + (u0 >> 1) + kq * 2);
        __hip_atomic_store(p, hp64, __ATOMIC_RELAXED, __HIP_MEMORY_SCOPE_AGENT);
      } else {
        const size_t yb = ((size_t)(t-1) * HID + u0 + kq * 4) * BATCH + b0 + rm;
        y[yb]             = unpk(hp.x, 0);
        y[yb + BATCH]     = unpk(hp.x, 1);
        y[yb + 2 * BATCH] = unpk(hp.y, 0);
        y[yb + 3 * BATCH] = unpk(hp.y, 1);
      }
    }
    // ---- continuous ready publish (steps <= t-2 visible at coherent point)
    if (tid == 0){
      if constexpr (MODE != 2){
        if (t >= 2)
          __hip_atomic_store(dst_ready, t - 1, __ATOMIC_RELAXED, __HIP_MEMORY_SCOPE_AGENT);
      }
      if constexpr (MODE != 0){
        if ((t & (CH-1)) == 0 && t > 0)
          __hip_atomic_store(src_done, t >> 3, __ATOMIC_RELAXED, __HIP_MEMORY_SCOPE_AGENT);
      }
    }
    // ---- back-pressure: cached; blocking refresh only if bound violated
    if constexpr (MODE != 2){
      if ((t & (CH-1)) == 0 && t >= RING){
        const int need = (t >> 3) - 7;
        if (dseen < need){
          dseen = aload(dst_done);
          while (dseen < need){ __builtin_amdgcn_s_sleep(8); dseen = aload(dst_done); }
        }
      }
    }
    // ---- pipelined flag check (need ring slot t+3 before issuing its load)
    if constexpr (MODE != 0){
      if (fpend > fseen) fseen = fpend;
      fpend = aload(src_ready);
      if (t + 3 < SEQ && fseen < t + 4){
        fseen = aload(src_ready);
        while (fseen < t + 4){ __builtin_amdgcn_s_sleep(2); fseen = aload(src_ready); }
      }
    }
    if (t + 3 < SEQ){
      if constexpr (MODE == 0) pfb = *xaddr(t + 3);
      else pgb = __hip_atomic_load(raddr(t + 3), __ATOMIC_RELAXED, __HIP_MEMORY_SCOPE_AGENT);
    }

    // ---- CRITICAL PATH: acc += Whh*h(t-1)  (4 dependent MFMAs per gate)
    #pragma unroll
    for (int s = 0; s < 4; ++s){
      const half8 bf = *(const half8*)(hbc + foff + s * 64);
      a0 = __builtin_amdgcn_mfma_f32_16x16x32_f16(whh[0][s], bf, a0, 0, 0, 0);
      a1 = __builtin_amdgcn_mfma_f32_16x16x32_f16(whh[1][s], bf, a1, 0, 0, 0);
      a2 = __builtin_amdgcn_mfma_f32_16x16x32_f16(whh[2][s], bf, a2, 0, 0, 0);
      a3 = __builtin_amdgcn_mfma_f32_16x16x32_f16(whh[3][s], bf, a3, 0, 0, 0);
    }

    // ---- elementwise (lane holds i,f,g,o for 4 units, 1 batch col)
    float hvr[4];
    #pragma unroll
    for (int r = 0; r < 4; ++r){
      const float ii = sigm(a0[r]), ff = sigm(a1[r]);
      const float gg = tanh_(a2[r]), oo = sigm(a3[r]);
      c4[r] = ff * c4[r] + ii * gg;
      hvr[r] = oo * tanh_(c4[r]);
    }
    hp.x = pack2f(hvr[0], hvr[1]);
    hp.y = pack2f(hvr[2], hvr[3]);

    // ---- h(t) -> LDS (next step's critical input)
    *(uint2*)(hbn + rm * XROW + u0 * 2 + kq * 8) = hp;

    // ---- stage x(t+2) -> xb[xw] (read next step, barrier-separated)
    if (t + 2 < SEQ){
      if constexpr (MODE == 0){
        uint2 p; p.x = pack2f(pfa.x, pfa.y); p.y = pack2f(pfa.z, pfa.w);
        *(uint2*)(xbw + sb * XROW + sk * 8) = p;
      } else {
        *(u64*)(xbw + sb * XROW + sk * 8) = pga;
      }
    }

    // ---- OFF-PATH: acc = bias + Wih*x(t+1) for the next step
    if (tn < SEQ){
      a0 = bias4[0]; a1 = bias4[1]; a2 = bias4[2]; a3 = bias4[3];
      #pragma unroll
      for (int s = 0; s < 4; ++s){
        const half8 bf = *(const half8*)(xbr + foff + s * 64);
        a0 = __builtin_amdgcn_mfma_f32_16x16x32_f16(wih[0][s], bf, a0, 0, 0, 0);
        a1 = __builtin_amdgcn_mfma_f32_16x16x32_f16(wih[1][s], bf, a1, 0, 0, 0);
        a2 = __builtin_amdgcn_mfma_f32_16x16x32_f16(wih[2][s], bf, a2, 0, 0, 0);
        a3 = __builtin_amdgcn_mfma_f32_16x16x32_f16(wih[3][s], bf, a3, 0, 0, 0);
      }
    }

    __syncthreads();
    pfa = pfb; pga = pgb;
    xr = (xr == 2) ? 0 : xr + 1;
    xw = (xw == 2) ? 0 : xw + 1;
    cur ^= 1;
  }

  // ---- tail: flush step SEQ-1, drain, final publishes
  if constexpr (MODE != 2){
    const u64 hp64 = ((u64)hp.y << 32) | (u64)hp.x;
    u64* p = (u64*)(rout + ((size_t)((SEQ-1) & (RING-1)) * BATCH + b0 + rm) * 64 + (u0 >> 1) + kq * 2);
    __hip_atomic_store(p, hp64, __ATOMIC_RELAXED, __HIP_MEMORY_SCOPE_AGENT);
  } else {
    const size_t yb = ((size_t)(SEQ-1) * HID + u0 + kq * 4) * BATCH + b0 + rm;
    y[yb]             = unpk(hp.x, 0);
    y[yb + BATCH]     = unpk(hp.x, 1);
    y[yb + 2 * BATCH] = unpk(hp.y, 0);
    y[yb + 3 * BATCH] = unpk(hp.y, 1);
  }
  __syncthreads();   // drains vmcnt: all stores complete
  if (tid == 0){
    if constexpr (MODE != 2)
      __hip_atomic_store(dst_ready, SEQ, __ATOMIC_RELAXED, __HIP_MEMORY_SCOPE_AGENT);
    if constexpr (MODE != 0)
      __hip_atomic_store(src_done, SEQ / CH, __ATOMIC_RELAXED, __HIP_MEMORY_SCOPE_AGENT);
  }
}

// Grid: 96 blocks (3 layers x 32 tiles) x 512 threads, (512,2): proven
// codegen shape (~128 arch VGPRs, weights register-resident, zero spill).
__global__ __launch_bounds__(512, 2) void lstm_pipe(
    const float* W0i, const float* W0h, const float* b0i, const float* b0h,
    const float* W1i, const float* W1h, const float* b1i, const float* b1h,
    const float* W2i, const float* W2h, const float* b2i, const float* b2h,
    const float* x, float* y, uint32_t* ring, int* flags)
{
  const int layer = blockIdx.x >> 5;   // 0,1,2
  const int tile  = blockIdx.x & 31;
  const int b0    = tile * BT;

  __shared__ char smem[5 * XSZ];       // xb[3] + hb[2] = 21760 B
  char* xb = smem;
  char* hb = smem + 3 * XSZ;

  uint32_t* r0 = ring;                                 // boundary 0: L0 -> L1
  uint32_t* r1 = ring + (size_t)RING * BATCH * 64;     // boundary 1: L1 -> L2

  int* p0 = flags + (0 * NTILE + tile) * FPAD;   // ready, boundary 0
  int* p1 = flags + (1 * NTILE + tile) * FPAD;   // ready, boundary 1
  int* c0 = flags + (2 * NTILE + tile) * FPAD;   // done,  boundary 0
  int* c1 = flags + (3 * NTILE + tile) * FPAD;   // done,  boundary 1

  if (layer == 0){
    run_layer<0>(W0i, W0h, b0i, b0h, x, nullptr, r0, nullptr,
                 nullptr, nullptr, p0, c0, b0, xb, hb);
  } else if (layer == 1){
    run_layer<1>(W1i, W1h, b1i, b1h, nullptr, r0, r1, nullptr,
                 p0, c0, p1, c1, b0, xb, hb);
  } else {
    run_layer<2>(W2i, W2h, b2i, b2h, nullptr, r1, nullptr, y,
                 p1, c1, nullptr, nullptr, b0, xb, hb);
  }
}

extern "C" void kernel_launch(void* const* d_in, const int* in_sizes, int n_in,
                              void* d_out, int out_size, void* d_ws, size_t ws_size,
                              hipStream_t stream) {
  const float* x    = (const float*)d_in[0];
  const float* Wih0 = (const float*)d_in[1];
  const float* Whh0 = (const float*)d_in[2];
  const float* bih0 = (const float*)d_in[3];
  const float* bhh0 = (const float*)d_in[4];
  const float* Wih1 = (const float*)d_in[5];
  const float* Whh1 = (const float*)d_in[6];
  const float* bih1 = (const float*)d_in[7];
  const float* bhh1 = (const float*)d_in[8];
  const float* Wih2 = (const float*)d_in[9];
  const float* Whh2 = (const float*)d_in[10];
  const float* bih2 = (const float*)d_in[11];
  const float* bhh2 = (const float*)d_in[12];

  float* out = (float*)d_out;
  uint32_t* ring = (uint32_t*)d_ws;
  const size_t ring_bytes = (size_t)2 * RING * BATCH * 64 * 4;   // 16 MiB
  int* flags = (int*)((char*)d_ws + ring_bytes);

  hipMemsetAsync(flags, 0, 4 * NTILE * FPAD * sizeof(int), stream);

  dim3 grid(3 * NTILE), block(512);
  lstm_pipe<<<grid, block, 0, stream>>>(
      Wih0, Whh0, bih0, bhh0, Wih1, Whh1, bih1, bhh1, Wih2, Whh2, bih2, bhh2,
      x, out, ring, flags);
}